// Round 8
// baseline (329.043 us; speedup 1.0000x reference)
//
#include <hip/hip_runtime.h>
#include <hip/hip_bf16.h>
#include <stdint.h>

#define NB 128
#define NL 32
#define NJ 31
#define NC 256
#define NCJ 128
#define LNEPS 1e-5f

typedef unsigned short u16;
typedef unsigned int u32;

using bf16x8 = __attribute__((ext_vector_type(8))) short;  // 8 bf16 in 4 VGPRs
using f32x4  = __attribute__((ext_vector_type(4))) float;  // MFMA accumulator

__device__ __forceinline__ u16 f2bf(float v) {
  __hip_bfloat16 h = __float2bfloat16(v);
  return __builtin_bit_cast(u16, h);
}
__device__ __forceinline__ float bf2f(u16 b) {
  __hip_bfloat16 h = __builtin_bit_cast(__hip_bfloat16, b);
  return __bfloat162float(h);
}

// 256-thread (4-wave) block reduction of (s, s2)
__device__ __forceinline__ void block_reduce2(float& s, float& s2, float* red, int t) {
  #pragma unroll
  for (int off = 32; off > 0; off >>= 1) {
    s  += __shfl_down(s, off);
    s2 += __shfl_down(s2, off);
  }
  int wid = t >> 6;
  if ((t & 63) == 0) { red[wid] = s; red[4 + wid] = s2; }
  __syncthreads();
  if (t == 0) {
    red[0] = red[0] + red[1] + red[2] + red[3];
    red[4] = red[4] + red[5] + red[6] + red[7];
  }
  __syncthreads();
  s = red[0]; s2 = red[4];
}

// ---- prepass: W fp32 -> bf16 in d_ws (12.19 MB) ----
__global__ __launch_bounds__(256) void convert_w(const float* __restrict__ W,
                                                 u16* __restrict__ Wb, int n) {
  const int i = (blockIdx.x * 256 + threadIdx.x) * 8;
  if (i + 8 > n) return;
  const float4 a = *reinterpret_cast<const float4*>(W + i);
  const float4 b = *reinterpret_cast<const float4*>(W + i + 4);
  uint4 o;
  o.x = (u32)f2bf(a.x) | ((u32)f2bf(a.y) << 16);
  o.y = (u32)f2bf(a.z) | ((u32)f2bf(a.w) << 16);
  o.z = (u32)f2bf(b.x) | ((u32)f2bf(b.y) << 16);
  o.w = (u32)f2bf(b.z) | ((u32)f2bf(b.w) << 16);
  *reinterpret_cast<uint4*>(Wb + i) = o;
}

// LDS B-operand layout: [n=16][k=768] bf16, row pitch 1536 B,
// byte addr = (n*1536 + k*2) ^ ((n&7)<<4)   (T2 swizzle, write==read)
template<bool USE_WS>
__global__ __launch_bounds__(256, 3) void rodrigues_mfma(
    const float* __restrict__ link,   // (B,L,C,16)
    const float* __restrict__ jf,     // (B,J,CJ)
    const float* __restrict__ W,      // (J,3,C,C) fp32
    const u16*   __restrict__ Wb,     // (J,3,C,C) bf16 (ws) or null
    const float* __restrict__ Kw,     // (J,16,CJ)
    const float* __restrict__ Kb,     // (J,16)
    const float* __restrict__ gam,    // (L, C*16)
    const float* __restrict__ bet,    // (L, C*16)
    const int* __restrict__ parent_idx,
    const int* __restrict__ child_idx,
    float* __restrict__ out)          // (B,L,C,16)
{
  __shared__ __align__(16) u16 Bh[16 * 768];  // 24 KB hi
  __shared__ __align__(16) u16 Bl[16 * 768];  // 24 KB lo
  __shared__ __align__(16) float jfs[NCJ];
  __shared__ float Ks[16], K2s[16];
  __shared__ float red[8];

  const int bx = blockIdx.x;
  const int t  = threadIdx.x;

  if (bx >= NJ * NB) {
    // ---- root block: out[b,0] = LN(link[b,0]), gamma/beta row 0 ----
    const int b = bx - NJ * NB;
    const float4* src4 = reinterpret_cast<const float4*>(link + (size_t)b * NL * 4096);
    float4 v[4];
    float s = 0.f, s2 = 0.f;
    #pragma unroll
    for (int i = 0; i < 4; ++i) {
      v[i] = src4[t + i * 256];
      s  += v[i].x + v[i].y + v[i].z + v[i].w;
      s2 += v[i].x * v[i].x + v[i].y * v[i].y + v[i].z * v[i].z + v[i].w * v[i].w;
    }
    block_reduce2(s, s2, red, t);
    const float mean = s * (1.f / 4096.f);
    const float var  = s2 * (1.f / 4096.f) - mean * mean;
    const float rstd = rsqrtf(var + LNEPS);
    const float4* g4 = reinterpret_cast<const float4*>(gam);
    const float4* b4 = reinterpret_cast<const float4*>(bet);
    float4* o4 = reinterpret_cast<float4*>(out + (size_t)b * NL * 4096);
    #pragma unroll
    for (int i = 0; i < 4; ++i) {
      const int f = t + i * 256;
      float4 g = g4[f], be = b4[f], o;
      o.x = (v[i].x - mean) * rstd * g.x + be.x;
      o.y = (v[i].y - mean) * rstd * g.y + be.y;
      o.z = (v[i].z - mean) * rstd * g.z + be.z;
      o.w = (v[i].w - mean) * rstd * g.w + be.w;
      o4[f] = o;
    }
    return;
  }

  const int j = bx / NB;   // j-major: blocks sharing W[j] cluster in time
  const int b = bx % NB;
  const int pj = parent_idx[j];
  const int cj = child_idx[j];

  // ---- stage joint feats (vectorized) ----
  if (t < 32) {
    reinterpret_cast<float4*>(jfs)[t] =
        reinterpret_cast<const float4*>(jf + ((size_t)b * NJ + j) * NCJ)[t];
  }
  __syncthreads();

  // ---- K = jf @ Kw^T + Kb : PARALLEL over all 256 threads ----
  // 16 entries x 16 threads each; each thread dots 8 elems, shfl-reduce width 16.
  {
    const int e = t >> 4;      // entry 0..15 (wave w covers entries 4w..4w+3)
    const int sub = t & 15;    // 16 lanes per entry
    const float* kwr = Kw + ((size_t)j * 16 + e) * NCJ + sub * 8;
    const float* jfp = jfs + sub * 8;
    float p = 0.f;
    #pragma unroll
    for (int q = 0; q < 8; ++q) p = fmaf(jfp[q], kwr[q], p);
    #pragma unroll
    for (int off = 8; off > 0; off >>= 1) p += __shfl_xor(p, off, 16);
    if (sub == 0) Ks[e] = p + Kb[j * 16 + e];
  }
  __syncthreads();
  if (t < 16) {
    const int x = t >> 2, y = t & 3;
    float a = 0.f;
    #pragma unroll
    for (int m = 0; m < 4; ++m) a = fmaf(Ks[x * 4 + m], Ks[m * 4 + y], a);
    K2s[t] = a;
  }
  __syncthreads();

  // ---- build B operand: rows k=(s,c): s0=Fp, s1=K*Fp, s2=K2*Fp; bf16 hi/lo split ----
  {
    const int c = t;
    const float* fp = link + ((size_t)b * NL + pj) * 4096 + c * 16;
    float f[16];
    #pragma unroll
    for (int i = 0; i < 4; ++i) {
      const float4 v = reinterpret_cast<const float4*>(fp)[i];
      f[4 * i + 0] = v.x; f[4 * i + 1] = v.y; f[4 * i + 2] = v.z; f[4 * i + 3] = v.w;
    }
    float kf[16], k2f[16];
    #pragma unroll
    for (int x = 0; x < 4; ++x)
      #pragma unroll
      for (int z = 0; z < 4; ++z) {
        float a1 = 0.f, a2 = 0.f;
        #pragma unroll
        for (int y = 0; y < 4; ++y) {
          a1 = fmaf(Ks[x * 4 + y],  f[y * 4 + z], a1);
          a2 = fmaf(K2s[x * 4 + y], f[y * 4 + z], a2);
        }
        kf[x * 4 + z] = a1;
        k2f[x * 4 + z] = a2;
      }
    char* bhB = reinterpret_cast<char*>(Bh);
    char* blB = reinterpret_cast<char*>(Bl);
    #pragma unroll
    for (int xz = 0; xz < 16; ++xz) {
      const int swz  = (xz & 7) << 4;
      const int rowb = xz * 1536;
      #pragma unroll
      for (int s = 0; s < 3; ++s) {
        const float v = (s == 0) ? f[xz] : (s == 1) ? kf[xz] : k2f[xz];
        const u16 h  = f2bf(v);
        const u16 lo = f2bf(v - bf2f(h));
        const int byte = (rowb + s * 512 + c * 2) ^ swz;
        *reinterpret_cast<u16*>(bhB + byte) = h;
        *reinterpret_cast<u16*>(blB + byte) = lo;
      }
    }
  }
  __syncthreads();

  // ---- MFMA GEMM: D[d, xz] = sum_k W[j,k(d-row)] * B[k][xz], K=768, 24 steps ----
  const int lane = t & 63;
  const int wv   = t >> 6;        // wave owns M-strip [wv*64, wv*64+64)
  const int rw   = lane & 15;     // A-row (d low), B-col (xz), D-col
  const int kg   = lane >> 4;     // k-group (8 consecutive k each)

  f32x4 acc[4];
  #pragma unroll
  for (int m = 0; m < 4; ++m) acc[m] = (f32x4){0.f, 0.f, 0.f, 0.f};

  const char* bhB = reinterpret_cast<const char*>(Bh);
  const char* blB = reinterpret_cast<const char*>(Bl);
  const int bframe = rw * 1536 + kg * 16;
  const int bswz   = (rw & 7) << 4;
  const int dbase  = wv * 64 + rw;

  if (USE_WS) {
    const u16* wj = Wb + (size_t)j * 3 * 65536;
    // software pipeline: depth-2 prefetch of global A-frags, depth-1 of LDS B-frags
    #define LOAD_AF(dst, kt2)                                                      \
      {                                                                            \
        const int s_ = (kt2) >> 3;                                                 \
        const int c0_ = ((kt2) & 7) * 32 + kg * 8;                                 \
        _Pragma("unroll")                                                          \
        for (int m = 0; m < 4; ++m) {                                              \
          const int d_ = dbase + m * 16;                                           \
          dst[m] = *reinterpret_cast<const bf16x8*>(                               \
              wj + (size_t)(s_ * 256 + d_) * 256 + c0_);                           \
        }                                                                          \
      }
    #define LOAD_B(bh_, bl_, kt2)                                                  \
      {                                                                            \
        const int bo_ = (bframe + (kt2) * 64) ^ bswz;                              \
        bh_ = *reinterpret_cast<const bf16x8*>(bhB + bo_);                         \
        bl_ = *reinterpret_cast<const bf16x8*>(blB + bo_);                         \
      }

    bf16x8 af0[4], af1[4], bh0, bl0;
    LOAD_AF(af0, 0);
    LOAD_AF(af1, 1);
    LOAD_B(bh0, bl0, 0);

    #pragma unroll 3
    for (int kt = 0; kt < 24; ++kt) {
      bf16x8 af2[4], bh1, bl1;
      const int kta = (kt + 2 < 24) ? kt + 2 : 23;
      const int ktb = (kt + 1 < 24) ? kt + 1 : 23;
      LOAD_AF(af2, kta);
      LOAD_B(bh1, bl1, ktb);
      #pragma unroll
      for (int m = 0; m < 4; ++m)
        acc[m] = __builtin_amdgcn_mfma_f32_16x16x32_bf16(af0[m], bh0, acc[m], 0, 0, 0);
      #pragma unroll
      for (int m = 0; m < 4; ++m)
        acc[m] = __builtin_amdgcn_mfma_f32_16x16x32_bf16(af0[m], bl0, acc[m], 0, 0, 0);
      #pragma unroll
      for (int m = 0; m < 4; ++m) { af0[m] = af1[m]; af1[m] = af2[m]; }
      bh0 = bh1; bl0 = bl1;
    }
    #undef LOAD_AF
    #undef LOAD_B
  } else {
    const float* wj = W + (size_t)j * 3 * 65536;
    for (int kt = 0; kt < 24; ++kt) {
      const int s  = kt >> 3;
      const int c0 = (kt & 7) * 32 + kg * 8;
      bf16x8 af[4];
      #pragma unroll
      for (int m = 0; m < 4; ++m) {
        const int d = dbase + m * 16;
        const float* p = wj + (size_t)(s * 256 + d) * 256 + c0;
        const float4 w0 = reinterpret_cast<const float4*>(p)[0];
        const float4 w1 = reinterpret_cast<const float4*>(p)[1];
        bf16x8 fr;
        fr[0] = (short)f2bf(w0.x); fr[1] = (short)f2bf(w0.y);
        fr[2] = (short)f2bf(w0.z); fr[3] = (short)f2bf(w0.w);
        fr[4] = (short)f2bf(w1.x); fr[5] = (short)f2bf(w1.y);
        fr[6] = (short)f2bf(w1.z); fr[7] = (short)f2bf(w1.w);
        af[m] = fr;
      }
      const int bo = (bframe + kt * 64) ^ bswz;
      const bf16x8 bh = *reinterpret_cast<const bf16x8*>(bhB + bo);
      const bf16x8 bl = *reinterpret_cast<const bf16x8*>(blB + bo);
      #pragma unroll
      for (int m = 0; m < 4; ++m)
        acc[m] = __builtin_amdgcn_mfma_f32_16x16x32_bf16(af[m], bh, acc[m], 0, 0, 0);
      #pragma unroll
      for (int m = 0; m < 4; ++m)
        acc[m] = __builtin_amdgcn_mfma_f32_16x16x32_bf16(af[m], bl, acc[m], 0, 0, 0);
    }
  }

  // ---- epilogue: comb = Fc + D, LayerNorm over 4096, write out[b, cj] ----
  // D element (m, r): row d = wv*64 + m*16 + kg*4 + r, col xz = rw
  const float* linkc = link + ((size_t)b * NL + cj) * 4096;
  float vals[16];
  float s = 0.f, s2 = 0.f;
  #pragma unroll
  for (int m = 0; m < 4; ++m) {
    #pragma unroll
    for (int r = 0; r < 4; ++r) {
      const int d = wv * 64 + m * 16 + kg * 4 + r;
      const float v = acc[m][r] + linkc[d * 16 + rw];
      vals[m * 4 + r] = v;
      s += v; s2 += v * v;
    }
  }
  block_reduce2(s, s2, red, t);
  const float mean = s * (1.f / 4096.f);
  const float var  = s2 * (1.f / 4096.f) - mean * mean;
  const float rstd = rsqrtf(var + LNEPS);

  const float* g  = gam + (size_t)cj * 4096;
  const float* be = bet + (size_t)cj * 4096;
  float* op = out + ((size_t)b * NL + cj) * 4096;
  #pragma unroll
  for (int m = 0; m < 4; ++m) {
    #pragma unroll
    for (int r = 0; r < 4; ++r) {
      const int d = wv * 64 + m * 16 + kg * 4 + r;
      const int e = d * 16 + rw;
      op[e] = (vals[m * 4 + r] - mean) * rstd * g[e] + be[e];
    }
  }
}

extern "C" void kernel_launch(void* const* d_in, const int* in_sizes, int n_in,
                              void* d_out, int out_size, void* d_ws, size_t ws_size,
                              hipStream_t stream) {
  const float* link = (const float*)d_in[0];
  const float* jf   = (const float*)d_in[1];
  const float* W    = (const float*)d_in[2];
  const float* Kw   = (const float*)d_in[3];
  const float* Kb   = (const float*)d_in[4];
  const float* gam  = (const float*)d_in[5];
  const float* bet  = (const float*)d_in[6];
  const int* pidx   = (const int*)d_in[7];
  const int* cidx   = (const int*)d_in[8];
  float* out = (float*)d_out;

  const int W_ELEMS = NJ * 3 * NC * NC;                 // 6,094,848
  const size_t WB_BYTES = (size_t)W_ELEMS * sizeof(u16); // 12,189,696
  const bool use_ws = (d_ws != nullptr) && (ws_size >= WB_BYTES);

  dim3 grid(NJ * NB + NB);  // 3968 child blocks (j-major) + 128 root LN blocks
  dim3 block(256);

  if (use_ws) {
    u16* Wb = (u16*)d_ws;
    dim3 pgrid(W_ELEMS / (256 * 8));  // 2976, exact
    hipLaunchKernelGGL(convert_w, pgrid, block, 0, stream, W, Wb, W_ELEMS);
    hipLaunchKernelGGL((rodrigues_mfma<true>), grid, block, 0, stream,
                       link, jf, W, (const u16*)Wb, Kw, Kb, gam, bet, pidx, cidx, out);
  } else {
    hipLaunchKernelGGL((rodrigues_mfma<false>), grid, block, 0, stream,
                       link, jf, W, (const u16*)nullptr, Kw, Kb, gam, bet, pidx, cidx, out);
  }
}

// Round 11
// 250.969 us; speedup vs baseline: 1.3111x; 1.3111x over previous
//
#include <hip/hip_runtime.h>
#include <hip/hip_bf16.h>
#include <stdint.h>

#define NB 128
#define NL 32
#define NJ 31
#define NC 256
#define NCJ 128
#define BG 4                 // batch elements per child block
#define NGB (NB / BG)        // 32 b-groups
#define NCHILD (NJ * NGB)    // 992 child blocks
#define LNEPS 1e-5f

typedef unsigned short u16;
typedef unsigned int u32;

using bf16x8 = __attribute__((ext_vector_type(8))) short;  // 8 bf16 in 4 VGPRs
using f32x4  = __attribute__((ext_vector_type(4))) float;  // MFMA accumulator

__device__ __forceinline__ u16 f2bf(float v) {
  __hip_bfloat16 h = __float2bfloat16(v);
  return __builtin_bit_cast(u16, h);
}
__device__ __forceinline__ float bf2f(u16 b) {
  __hip_bfloat16 h = __builtin_bit_cast(__hip_bfloat16, b);
  return __bfloat162float(h);
}

// 256-thread (4-wave) block reduction of (s, s2) — root path only
__device__ __forceinline__ void block_reduce2(float& s, float& s2, float* red, int t) {
  #pragma unroll
  for (int off = 32; off > 0; off >>= 1) {
    s  += __shfl_down(s, off);
    s2 += __shfl_down(s2, off);
  }
  int wid = t >> 6;
  if ((t & 63) == 0) { red[wid] = s; red[4 + wid] = s2; }
  __syncthreads();
  if (t == 0) {
    red[0] = red[0] + red[1] + red[2] + red[3];
    red[4] = red[4] + red[5] + red[6] + red[7];
  }
  __syncthreads();
  s = red[0]; s2 = red[4];
}

// ---- prepass: W fp32 -> bf16 in d_ws (12.19 MB) ----
__global__ __launch_bounds__(256) void convert_w(const float* __restrict__ W,
                                                 u16* __restrict__ Wb, int n) {
  const int i = (blockIdx.x * 256 + threadIdx.x) * 8;
  if (i + 8 > n) return;
  const float4 a = *reinterpret_cast<const float4*>(W + i);
  const float4 b = *reinterpret_cast<const float4*>(W + i + 4);
  uint4 o;
  o.x = (u32)f2bf(a.x) | ((u32)f2bf(a.y) << 16);
  o.y = (u32)f2bf(a.z) | ((u32)f2bf(a.w) << 16);
  o.z = (u32)f2bf(b.x) | ((u32)f2bf(b.y) << 16);
  o.w = (u32)f2bf(b.z) | ((u32)f2bf(b.w) << 16);
  *reinterpret_cast<uint4*>(Wb + i) = o;
}

// Child block: j x (4 b's). GEMM M=256 (d), N=64 (b*16+xz), K=768 in 12 chunks of 64.
// LDS W chunk  [row=256][k=64] bf16: byte = row*128 + k*2, ^ ((row&7)<<4)
// LDS B chunks [n=64][k=64] bf16 hi/lo: byte = n*128 + k*2, ^ ((n&7)<<4)
template<bool USE_WS>
__global__ __launch_bounds__(256, 3) void rodrigues_mfma(
    const float* __restrict__ link,   // (B,L,C,16)
    const float* __restrict__ jf,     // (B,J,CJ)
    const float* __restrict__ W,      // (J,3,C,C) fp32
    const u16*   __restrict__ Wb,     // (J,3,C,C) bf16 (ws) or null
    const float* __restrict__ Kw,     // (J,16,CJ)
    const float* __restrict__ Kb,     // (J,16)
    const float* __restrict__ gam,    // (L, C*16)
    const float* __restrict__ bet,    // (L, C*16)
    const int* __restrict__ parent_idx,
    const int* __restrict__ child_idx,
    float* __restrict__ out)          // (B,L,C,16)
{
  __shared__ __align__(16) u16 Wc[256 * 64];   // 32 KB
  __shared__ __align__(16) u16 BhS[64 * 64];   // 8 KB
  __shared__ __align__(16) u16 BlS[64 * 64];   // 8 KB
  __shared__ __align__(16) float jfs[BG][NCJ]; // 2 KB
  __shared__ float Ks[BG][16], K2s[BG][16];
  __shared__ float redS[4][4], redS2[4][4];    // [wm][nt]
  __shared__ float rootred[8];

  const int bx = blockIdx.x;
  const int t  = threadIdx.x;

  if (bx >= NCHILD) {
    // ---- root block: out[b,0] = LN(link[b,0]), gamma/beta row 0 ----
    const int b = bx - NCHILD;
    const float4* src4 = reinterpret_cast<const float4*>(link + (size_t)b * NL * 4096);
    float4 v[4];
    float s = 0.f, s2 = 0.f;
    #pragma unroll
    for (int i = 0; i < 4; ++i) {
      v[i] = src4[t + i * 256];
      s  += v[i].x + v[i].y + v[i].z + v[i].w;
      s2 += v[i].x * v[i].x + v[i].y * v[i].y + v[i].z * v[i].z + v[i].w * v[i].w;
    }
    block_reduce2(s, s2, rootred, t);
    const float mean = s * (1.f / 4096.f);
    const float var  = s2 * (1.f / 4096.f) - mean * mean;
    const float rstd = rsqrtf(var + LNEPS);
    const float4* g4 = reinterpret_cast<const float4*>(gam);
    const float4* b4 = reinterpret_cast<const float4*>(bet);
    float4* o4 = reinterpret_cast<float4*>(out + (size_t)b * NL * 4096);
    #pragma unroll
    for (int i = 0; i < 4; ++i) {
      const int f = t + i * 256;
      float4 g = g4[f], be = b4[f], o;
      o.x = (v[i].x - mean) * rstd * g.x + be.x;
      o.y = (v[i].y - mean) * rstd * g.y + be.y;
      o.z = (v[i].z - mean) * rstd * g.z + be.z;
      o.w = (v[i].w - mean) * rstd * g.w + be.w;
      o4[f] = o;
    }
    return;
  }

  const int j  = bx / NGB;           // j-major: 32 consecutive blocks share W[j]
  const int b0 = (bx % NGB) * BG;
  const int pj = parent_idx[j];
  const int cj = child_idx[j];

  // ---- stage joint feats for 4 b's ----
  if (t < 128) {
    const int b = t >> 5, q = t & 31;
    reinterpret_cast<float4*>(jfs[b])[q] =
        reinterpret_cast<const float4*>(jf + ((size_t)(b0 + b) * NJ + j) * NCJ)[q];
  }
  __syncthreads();

  // ---- K mats: 64 (b,e) pairs x 4 lanes, 32-elem dots + width-4 reduce ----
  {
    const int pair = t >> 2, sub = t & 3;
    const int b = pair >> 4, e = pair & 15;
    const float* kwr = Kw + ((size_t)j * 16 + e) * NCJ + sub * 32;
    const float* jfp = jfs[b] + sub * 32;
    float p = 0.f;
    #pragma unroll
    for (int q = 0; q < 32; ++q) p = fmaf(jfp[q], kwr[q], p);
    p += __shfl_xor(p, 1, 4);
    p += __shfl_xor(p, 2, 4);
    if (sub == 0) Ks[b][e] = p + Kb[j * 16 + e];
  }
  __syncthreads();
  if (t < 64) {
    const int b = t >> 4, e = t & 15, x = e >> 2, y = e & 3;
    float a = 0.f;
    #pragma unroll
    for (int m2 = 0; m2 < 4; ++m2) a = fmaf(Ks[b][x * 4 + m2], Ks[b][m2 * 4 + y], a);
    K2s[b][e] = a;
  }
  __syncthreads();

  const int wm   = t >> 6;        // wave = M-strip [wm*64, wm*64+64)
  const int lane = t & 63;
  const int rw   = lane & 15;     // frag row/col index
  const int kg   = lane >> 4;     // frag k-group (8 consecutive k)
  const int bb   = t >> 6;        // B-stage: b index (wave-sized groups)
  const int cc_  = t & 63;        // B-stage: c within chunk

  f32x4 acc[4][4];
  #pragma unroll
  for (int m = 0; m < 4; ++m)
    #pragma unroll
    for (int nt = 0; nt < 4; ++nt) acc[m][nt] = (f32x4){0.f, 0.f, 0.f, 0.f};

  for (int kc = 0; kc < 12; ++kc) {
    const int s  = kc >> 2;
    const int c0 = (kc & 3) << 6;

    // ---- stage W chunk: [256 rows][64 k] bf16, swizzled ----
    if (USE_WS) {
      const u16* wsrc = Wb + (size_t)j * 3 * 65536 + (size_t)s * 65536 + c0;
      #pragma unroll
      for (int i = 0; i < 8; ++i) {
        const int cid = i * 256 + t, row = cid >> 3, ch = cid & 7;
        const bf16x8 v = *reinterpret_cast<const bf16x8*>(wsrc + (size_t)row * 256 + ch * 8);
        const int byte = (row * 128 + ch * 16) ^ ((row & 7) << 4);
        *reinterpret_cast<bf16x8*>(reinterpret_cast<char*>(Wc) + byte) = v;
      }
    } else {
      const float* wsrc = W + (size_t)j * 3 * 65536 + (size_t)s * 65536 + c0;
      #pragma unroll
      for (int i = 0; i < 8; ++i) {
        const int cid = i * 256 + t, row = cid >> 3, ch = cid & 7;
        const float* p = wsrc + (size_t)row * 256 + ch * 8;
        const float4 w0 = reinterpret_cast<const float4*>(p)[0];
        const float4 w1 = reinterpret_cast<const float4*>(p)[1];
        bf16x8 v;
        v[0] = (short)f2bf(w0.x); v[1] = (short)f2bf(w0.y);
        v[2] = (short)f2bf(w0.z); v[3] = (short)f2bf(w0.w);
        v[4] = (short)f2bf(w1.x); v[5] = (short)f2bf(w1.y);
        v[6] = (short)f2bf(w1.z); v[7] = (short)f2bf(w1.w);
        const int byte = (row * 128 + ch * 16) ^ ((row & 7) << 4);
        *reinterpret_cast<bf16x8*>(reinterpret_cast<char*>(Wc) + byte) = v;
      }
    }

    // ---- stage B chunk: rows n=(b,xz), k=c; value = (K^s * Fp)[c][xz], hi/lo split ----
    {
      const int cc = c0 + cc_;
      const float* fp = link + ((size_t)(b0 + bb) * NL + pj) * 4096 + cc * 16;
      float f[16];
      #pragma unroll
      for (int i = 0; i < 4; ++i) {
        const float4 vv = reinterpret_cast<const float4*>(fp)[i];
        f[4 * i + 0] = vv.x; f[4 * i + 1] = vv.y; f[4 * i + 2] = vv.z; f[4 * i + 3] = vv.w;
      }
      float v[16];
      if (s == 0) {
        #pragma unroll
        for (int e = 0; e < 16; ++e) v[e] = f[e];
      } else {
        const float* Km = (s == 1) ? Ks[bb] : K2s[bb];
        #pragma unroll
        for (int x = 0; x < 4; ++x)
          #pragma unroll
          for (int z = 0; z < 4; ++z) {
            float a1 = 0.f;
            #pragma unroll
            for (int y = 0; y < 4; ++y) a1 = fmaf(Km[x * 4 + y], f[y * 4 + z], a1);
            v[x * 4 + z] = a1;
          }
      }
      char* bhB = reinterpret_cast<char*>(BhS);
      char* blB = reinterpret_cast<char*>(BlS);
      const int n0 = bb * 16;
      #pragma unroll
      for (int xz = 0; xz < 16; ++xz) {
        const int n = n0 + xz;
        const u16 h  = f2bf(v[xz]);
        const u16 lo = f2bf(v[xz] - bf2f(h));
        const int byte = (n * 128 + cc_ * 2) ^ ((n & 7) << 4);
        *reinterpret_cast<u16*>(bhB + byte) = h;
        *reinterpret_cast<u16*>(blB + byte) = lo;
      }
    }
    __syncthreads();

    // ---- compute: 2 k-steps of 32, 4m x 4n tiles per wave ----
    #pragma unroll
    for (int kt = 0; kt < 2; ++kt) {
      bf16x8 a[4], bh[4], bl[4];
      #pragma unroll
      for (int m = 0; m < 4; ++m) {
        const int row = wm * 64 + m * 16 + rw;
        const int byte = (row * 128 + (kt * 4 + kg) * 16) ^ ((row & 7) << 4);
        a[m] = *reinterpret_cast<const bf16x8*>(reinterpret_cast<const char*>(Wc) + byte);
      }
      #pragma unroll
      for (int nt = 0; nt < 4; ++nt) {
        const int n = nt * 16 + rw;
        const int byte = (n * 128 + (kt * 4 + kg) * 16) ^ ((n & 7) << 4);
        bh[nt] = *reinterpret_cast<const bf16x8*>(reinterpret_cast<const char*>(BhS) + byte);
        bl[nt] = *reinterpret_cast<const bf16x8*>(reinterpret_cast<const char*>(BlS) + byte);
      }
      #pragma unroll
      for (int m = 0; m < 4; ++m)
        #pragma unroll
        for (int nt = 0; nt < 4; ++nt) {
          acc[m][nt] = __builtin_amdgcn_mfma_f32_16x16x32_bf16(a[m], bh[nt], acc[m][nt], 0, 0, 0);
          acc[m][nt] = __builtin_amdgcn_mfma_f32_16x16x32_bf16(a[m], bl[nt], acc[m][nt], 0, 0, 0);
        }
    }
    __syncthreads();   // protect LDS before next chunk's staging
  }

  // ---- epilogue: comb = Fc + D, per-b LayerNorm over 4096, write out[b, cj] ----
  // D element (m, nt, r): d = wm*64 + m*16 + kg*4 + r; b = b0+nt; xz = rw
  float sA[4] = {0.f, 0.f, 0.f, 0.f}, sB[4] = {0.f, 0.f, 0.f, 0.f};
  #pragma unroll
  for (int nt = 0; nt < 4; ++nt) {
    const float* lc = link + ((size_t)(b0 + nt) * NL + cj) * 4096;
    #pragma unroll
    for (int m = 0; m < 4; ++m)
      #pragma unroll
      for (int r = 0; r < 4; ++r) {
        const int d = wm * 64 + m * 16 + kg * 4 + r;
        const float v = acc[m][nt][r] + lc[d * 16 + rw];
        acc[m][nt][r] = v;
        sA[nt] += v; sB[nt] += v * v;
      }
  }
  #pragma unroll
  for (int off = 32; off > 0; off >>= 1) {
    #pragma unroll
    for (int nt = 0; nt < 4; ++nt) {
      sA[nt] += __shfl_down(sA[nt], off);
      sB[nt] += __shfl_down(sB[nt], off);
    }
  }
  if (lane == 0) {
    #pragma unroll
    for (int nt = 0; nt < 4; ++nt) { redS[wm][nt] = sA[nt]; redS2[wm][nt] = sB[nt]; }
  }
  __syncthreads();
  float mean[4], rstd[4];
  #pragma unroll
  for (int nt = 0; nt < 4; ++nt) {
    const float st  = redS[0][nt] + redS[1][nt] + redS[2][nt] + redS[3][nt];
    const float st2 = redS2[0][nt] + redS2[1][nt] + redS2[2][nt] + redS2[3][nt];
    mean[nt] = st * (1.f / 4096.f);
    const float var = st2 * (1.f / 4096.f) - mean[nt] * mean[nt];
    rstd[nt] = rsqrtf(var + LNEPS);
  }
  const float* g  = gam + (size_t)cj * 4096;
  const float* be = bet + (size_t)cj * 4096;
  #pragma unroll
  for (int nt = 0; nt < 4; ++nt) {
    float* op = out + ((size_t)(b0 + nt) * NL + cj) * 4096;
    #pragma unroll
    for (int m = 0; m < 4; ++m)
      #pragma unroll
      for (int r = 0; r < 4; ++r) {
        const int d = wm * 64 + m * 16 + kg * 4 + r;
        const int e = d * 16 + rw;
        op[e] = (acc[m][nt][r] - mean[nt]) * rstd[nt] * g[e] + be[e];
      }
  }
}

extern "C" void kernel_launch(void* const* d_in, const int* in_sizes, int n_in,
                              void* d_out, int out_size, void* d_ws, size_t ws_size,
                              hipStream_t stream) {
  const float* link = (const float*)d_in[0];
  const float* jf   = (const float*)d_in[1];
  const float* W    = (const float*)d_in[2];
  const float* Kw   = (const float*)d_in[3];
  const float* Kb   = (const float*)d_in[4];
  const float* gam  = (const float*)d_in[5];
  const float* bet  = (const float*)d_in[6];
  const int* pidx   = (const int*)d_in[7];
  const int* cidx   = (const int*)d_in[8];
  float* out = (float*)d_out;

  const int W_ELEMS = NJ * 3 * NC * NC;                  // 6,094,848
  const size_t WB_BYTES = (size_t)W_ELEMS * sizeof(u16); // 12,189,696
  const bool use_ws = (d_ws != nullptr) && (ws_size >= WB_BYTES);

  dim3 grid(NCHILD + NB);  // 992 child blocks (j-major, 4 b's each) + 128 root blocks
  dim3 block(256);

  if (use_ws) {
    u16* Wb = (u16*)d_ws;
    dim3 pgrid(W_ELEMS / (256 * 8));  // 2976, exact
    hipLaunchKernelGGL(convert_w, pgrid, block, 0, stream, W, Wb, W_ELEMS);
    hipLaunchKernelGGL((rodrigues_mfma<true>), grid, block, 0, stream,
                       link, jf, W, (const u16*)Wb, Kw, Kb, gam, bet, pidx, cidx, out);
  } else {
    hipLaunchKernelGGL((rodrigues_mfma<false>), grid, block, 0, stream,
                       link, jf, W, (const u16*)nullptr, Kw, Kb, gam, bet, pidx, cidx, out);
  }
}